// Round 11
// baseline (676.784 us; speedup 1.0000x reference)
//
#include <hip/hip_runtime.h>

typedef _Float16 f16x8 __attribute__((ext_vector_type(8)));
typedef float    f32x4 __attribute__((ext_vector_type(4)));

#define NSTEP 512

// 7-trans LSTM activation (validated R8-R10: absmax 6.1e-5 over 512 steps).
// eo hoisted before the c-chain to shorten serial latency.
__device__ __forceinline__ float lstm_act_(float gi, float gf, float gg, float go, float& c) {
    float eg = __expf(fminf(gg + gg, 21.0f));
    float ei = __expf(fminf(-gi, 21.0f));
    float ef = __expf(fminf(-gf, 21.0f));
    float eo = __expf(fminf(-go, 21.0f));
    float X  = (eg + 1.0f) * (1.0f + ei);
    float Y  = 1.0f + ef;
    float r  = __builtin_amdgcn_rcpf(X * Y);
    c = fmaf(r * X, c, (eg - 1.0f) * (r * Y));
    float ec = __expf(fminf(c + c, 21.0f));
    float r2 = __builtin_amdgcn_rcpf((ec + 1.0f) * (1.0f + eo));
    return (ec - 1.0f) * r2;
}
__device__ __forceinline__ float sig_(float v) {
    return __builtin_amdgcn_rcpf(1.0f + __expf(-v));
}
__device__ __forceinline__ float tanh_(float v) {
    return 1.0f - 2.0f * __builtin_amdgcn_rcpf(__expf(v + v) + 1.0f);
}

// 512 threads = 8 waves, grid 128. Each block: 32 batches = two INDEPENDENT
// 16-batch groups G0 (batch cols 0..15) / G1 (16..31), software-pipelined in
// half-step intervals:
//   interval A: G0-MFMA(step i)  + G1-acts(step i-1)   + barrier
//   interval B: G1-MFMA(step i)  + G0-acts(step i)     + barrier
// Per-interval per-wave issue == R9's per-step (12 full-width MFMA, 2 acts,
// 2 ds_read_b128) — NOTHING duplicated; the act-group's gates are in registers
// at interval start, so the mfma-group's ds_read->MFMA chain drains under the
// act burst and leaves the critical path.
// Tiles (R9 mapping): wave w owns tiles {2w,2w+1}; tile-row = usub*4+gate ->
// acc[r] = gate r of unit u_tt = 8w+4tt+q, batch m. Panels fragment-major
// P[kc][q][batch][jj] (lane-linear conflict-free reads), SINGLE-buffered per
// group (read-interval and write-interval are barrier-separated).
// Precision: f16 2-pass weight split W = Whi + Wlo*2^-11 (identical to R9).
__global__ __launch_bounds__(512, 1) void lstm_pipe_kernel(
    const float* __restrict__ x,     const float* __restrict__ Wemb,
    const float* __restrict__ Wih1,  const float* __restrict__ Whh1,
    const float* __restrict__ b1,    const float* __restrict__ Wih2,
    const float* __restrict__ b2,    const float* __restrict__ Wout,
    const float* __restrict__ bout,  float* __restrict__ out)
{
    __shared__ __align__(16) _Float16 P0[2][4][16][8];   // 2048 B, [kc][q][batch][jj]
    __shared__ __align__(16) _Float16 P1[2][4][16][8];   // 2048 B
    __shared__ __align__(16) float h2tmp[32 * 64];       // 8192 B
    __shared__ __align__(16) float h2s[256 * 32];        // 32768 B
    __shared__ float part[16 * 32 * 2];                  // 4096 B

    const int t = threadIdx.x;
    const int l = t & 63;
    const int w = t >> 6;        // wave 0..7
    const int m = l & 15;        // tile A-row / B col (batch) / D col
    const int q = l >> 4;        // quad
    const int b0 = blockIdx.x * 32;

    // ---- weight fragments (f16 hi + lo*2048); chunk 0 = emb, 1,2 = h -------
    f16x8 wh[2][3], wl[2][3];
    #pragma unroll
    for (int tt = 0; tt < 2; ++tt) {
        const int n = (m & 3) * 64 + (2 * w + tt) * 4 + (m >> 2);  // gate-row
        #pragma unroll
        for (int c = 0; c < 3; ++c) {
            #pragma unroll
            for (int jj = 0; jj < 8; ++jj) {
                int kk = (q << 3) + jj;
                float v = 0.0f;
                if (c == 0) { if (kk < 20) v = Wih1[n * 20 + kk]; }
                else        { v = Whh1[n * 64 + (c - 1) * 32 + kk]; }
                _Float16 hi = (_Float16)v;
                wh[tt][c][jj] = hi;
                wl[tt][c][jj] = (_Float16)((v - (float)hi) * 2048.0f);
            }
        }
    }
    f32x4 bias4[2];
    #pragma unroll
    for (int tt = 0; tt < 2; ++tt)
        #pragma unroll
        for (int r = 0; r < 4; ++r)
            bias4[tt][r] = b1[r * 64 + (2 * w + tt) * 4 + q];
    const f32x4 z4 = {0.f, 0.f, 0.f, 0.f};

    // ---- per-lane emb machinery --------------------------------------------
    float wea[8], web[8];
    #pragma unroll
    for (int jj = 0; jj < 8; ++jj) {
        int k = (q << 3) + jj;
        wea[jj] = (k < 20) ? Wemb[2 * k]     : 0.0f;
        web[jj] = (k < 20) ? Wemb[2 * k + 1] : 0.0f;
    }
    const float* xrow0 = x + (size_t)(b0 + m)      * (2 * NSTEP);
    const float* xrow1 = x + (size_t)(b0 + 16 + m) * (2 * NSTEP);

    // ---- zero both panels (h(-1) = 0) --------------------------------------
    for (int idx = t; idx < 2 * 4 * 16 * 8; idx += 512) {
        ((_Float16*)P0)[idx] = (_Float16)0.0f;
        ((_Float16*)P1)[idx] = (_Float16)0.0f;
    }

    // ---- preamble: ef0(0); x prefetches ------------------------------------
    f16x8 ef0, ef1;
    {
        float xa = xrow0[0], xb = xrow0[1];
        #pragma unroll
        for (int jj = 0; jj < 8; ++jj)
            ef0[jj] = (_Float16)fmaxf(fmaf(xa, wea[jj], xb * web[jj]), 0.0f);
    }
    float xa0 = xrow0[2], xb0 = xrow0[3];    // G0 token 1 (for ef0(1))
    float xa1 = xrow1[0], xb1 = xrow1[1];    // G1 token 0 (for ef1(0))
    __syncthreads();

    f32x4 A0h[2], A0l[2], A1h[2], A1l[2];
    float cst0[2] = {0.f, 0.f}, cst1[2] = {0.f, 0.f};

    for (int i = 0; i < NSTEP; ++i) {
        // ============== interval A: G0-MFMA(i) + G1-acts(i-1) ==============
        {
            const _Float16* base = &P0[0][q][m][0];
            f16x8 f0 = *(const f16x8*)(base);
            f16x8 f1 = *(const f16x8*)(base + 512);      // kc=1 plane

            #pragma unroll
            for (int tt = 0; tt < 2; ++tt) {
                A0h[tt] = __builtin_amdgcn_mfma_f32_16x16x32_f16(wh[tt][0], ef0, bias4[tt], 0, 0, 0);
                A0l[tt] = __builtin_amdgcn_mfma_f32_16x16x32_f16(wl[tt][0], ef0, z4, 0, 0, 0);
            }

            // G1 acts for step i-1 (gates already in registers)
            if (i > 0) {
                #pragma unroll
                for (int tt = 0; tt < 2; ++tt) {
                    float gi = fmaf(0x1p-11f, A1l[tt][0], A1h[tt][0]);
                    float gf = fmaf(0x1p-11f, A1l[tt][1], A1h[tt][1]);
                    float gg = fmaf(0x1p-11f, A1l[tt][2], A1h[tt][2]);
                    float go = fmaf(0x1p-11f, A1l[tt][3], A1h[tt][3]);
                    float hv = lstm_act_(gi, gf, gg, go, cst1[tt]);
                    int u = 8 * w + 4 * tt + q;
                    P1[u >> 5][(u >> 3) & 3][m][u & 7] = (_Float16)hv;
                }
            }
            // build ef1(i) from held G1 token i, then prefetch G1 token i+1
            #pragma unroll
            for (int jj = 0; jj < 8; ++jj)
                ef1[jj] = (_Float16)fmaxf(fmaf(xa1, wea[jj], xb1 * web[jj]), 0.0f);
            int ns = (i + 1 < NSTEP) ? i + 1 : NSTEP - 1;
            xa1 = xrow1[2 * ns]; xb1 = xrow1[2 * ns + 1];

            // G0 h-chunk MFMAs (ds_read drained under the act burst above)
            #pragma unroll
            for (int tt = 0; tt < 2; ++tt) {
                A0h[tt] = __builtin_amdgcn_mfma_f32_16x16x32_f16(wh[tt][1], f0, A0h[tt], 0, 0, 0);
                A0l[tt] = __builtin_amdgcn_mfma_f32_16x16x32_f16(wl[tt][1], f0, A0l[tt], 0, 0, 0);
                A0h[tt] = __builtin_amdgcn_mfma_f32_16x16x32_f16(wh[tt][2], f1, A0h[tt], 0, 0, 0);
                A0l[tt] = __builtin_amdgcn_mfma_f32_16x16x32_f16(wl[tt][2], f1, A0l[tt], 0, 0, 0);
            }
        }
        __syncthreads();

        // ============== interval B: G1-MFMA(i) + G0-acts(i) ================
        {
            const _Float16* base = &P1[0][q][m][0];
            f16x8 f0 = *(const f16x8*)(base);
            f16x8 f1 = *(const f16x8*)(base + 512);

            #pragma unroll
            for (int tt = 0; tt < 2; ++tt) {
                A1h[tt] = __builtin_amdgcn_mfma_f32_16x16x32_f16(wh[tt][0], ef1, bias4[tt], 0, 0, 0);
                A1l[tt] = __builtin_amdgcn_mfma_f32_16x16x32_f16(wl[tt][0], ef1, z4, 0, 0, 0);
            }

            // G0 acts for step i
            #pragma unroll
            for (int tt = 0; tt < 2; ++tt) {
                float gi = fmaf(0x1p-11f, A0l[tt][0], A0h[tt][0]);
                float gf = fmaf(0x1p-11f, A0l[tt][1], A0h[tt][1]);
                float gg = fmaf(0x1p-11f, A0l[tt][2], A0h[tt][2]);
                float go = fmaf(0x1p-11f, A0l[tt][3], A0h[tt][3]);
                float hv = lstm_act_(gi, gf, gg, go, cst0[tt]);
                int u = 8 * w + 4 * tt + q;
                P0[u >> 5][(u >> 3) & 3][m][u & 7] = (_Float16)hv;
            }
            // build ef0(i+1) from held G0 token i+1, prefetch token i+2
            #pragma unroll
            for (int jj = 0; jj < 8; ++jj)
                ef0[jj] = (_Float16)fmaxf(fmaf(xa0, wea[jj], xb0 * web[jj]), 0.0f);
            int ns = (i + 2 < NSTEP) ? i + 2 : NSTEP - 1;
            xa0 = xrow0[2 * ns]; xb0 = xrow0[2 * ns + 1];

            // G1 h-chunk MFMAs
            #pragma unroll
            for (int tt = 0; tt < 2; ++tt) {
                A1h[tt] = __builtin_amdgcn_mfma_f32_16x16x32_f16(wh[tt][1], f0, A1h[tt], 0, 0, 0);
                A1l[tt] = __builtin_amdgcn_mfma_f32_16x16x32_f16(wl[tt][1], f0, A1l[tt], 0, 0, 0);
                A1h[tt] = __builtin_amdgcn_mfma_f32_16x16x32_f16(wh[tt][2], f1, A1h[tt], 0, 0, 0);
                A1l[tt] = __builtin_amdgcn_mfma_f32_16x16x32_f16(wl[tt][2], f1, A1l[tt], 0, 0, 0);
            }
        }
        __syncthreads();
    }

    // ---- tail: G1 acts for step 511 ----------------------------------------
    #pragma unroll
    for (int tt = 0; tt < 2; ++tt) {
        float gi = fmaf(0x1p-11f, A1l[tt][0], A1h[tt][0]);
        float gf = fmaf(0x1p-11f, A1l[tt][1], A1h[tt][1]);
        float gg = fmaf(0x1p-11f, A1l[tt][2], A1h[tt][2]);
        float go = fmaf(0x1p-11f, A1l[tt][3], A1h[tt][3]);
        float hv = lstm_act_(gi, gf, gg, go, cst1[tt]);
        int u = 8 * w + 4 * tt + q;
        P1[u >> 5][(u >> 3) & 3][m][u & 7] = (_Float16)hv;
    }
    __syncthreads();

    // ---- epilogue: h64 (32 batches) to fp32 --------------------------------
    #pragma unroll
    for (int rep = 0; rep < 4; ++rep) {
        int idx = t + rep * 512;                 // 2048 values
        int b = idx >> 6, k = idx & 63;
        float v = (b < 16) ? (float)P0[k >> 5][(k >> 3) & 3][b][k & 7]
                           : (float)P1[k >> 5][(k >> 3) & 3][b - 16][k & 7];
        h2tmp[idx] = v;
    }
    __syncthreads();

    // ---- LSTM2 (single step, h=c=0 -> f-gate irrelevant) -------------------
    {
        const int u = t & 255;
        const int bh0 = (t >> 8) * 16;           // 16 batches per thread-half
        float acci[16], accg[16], acco[16];
        float bi2 = b2[u], bg2 = b2[512 + u], bo2 = b2[768 + u];
        #pragma unroll
        for (int b = 0; b < 16; ++b) { acci[b] = bi2; accg[b] = bg2; acco[b] = bo2; }
        for (int k4 = 0; k4 < 64; k4 += 4) {
            float4 wi = *(const float4*)&Wih2[(size_t)u * 64 + k4];
            float4 wg = *(const float4*)&Wih2[(size_t)(512 + u) * 64 + k4];
            float4 wo = *(const float4*)&Wih2[(size_t)(768 + u) * 64 + k4];
            #pragma unroll
            for (int b = 0; b < 16; ++b) {
                float4 hb = *(const float4*)&h2tmp[(bh0 + b) * 64 + k4];
                acci[b] += wi.x * hb.x + wi.y * hb.y + wi.z * hb.z + wi.w * hb.w;
                accg[b] += wg.x * hb.x + wg.y * hb.y + wg.z * hb.z + wg.w * hb.w;
                acco[b] += wo.x * hb.x + wo.y * hb.y + wo.z * hb.z + wo.w * hb.w;
            }
        }
        #pragma unroll
        for (int b = 0; b < 16; ++b) {
            float c2 = sig_(acci[b]) * tanh_(accg[b]);
            h2s[u * 32 + bh0 + b] = sig_(acco[b]) * tanh_(c2);
        }
    }
    __syncthreads();

    // ---- output projection --------------------------------------------------
    {
        int b = t & 31, grp = t >> 5;            // 16 groups x 16 units
        float p0 = 0.f, p1 = 0.f;
        for (int uu = grp * 16; uu < grp * 16 + 16; ++uu) {
            float hvv = h2s[uu * 32 + b];
            p0 += hvv * Wout[uu];
            p1 += hvv * Wout[256 + uu];
        }
        part[(grp * 32 + b) * 2 + 0] = p0;
        part[(grp * 32 + b) * 2 + 1] = p1;
    }
    __syncthreads();
    if (t < 64) {
        int b = t >> 1, o = t & 1;
        float s0 = bout[o];
        for (int grp = 0; grp < 16; ++grp) s0 += part[(grp * 32 + b) * 2 + o];
        out[(size_t)(b0 + b) * 2 + o] = s0;
    }
}

extern "C" void kernel_launch(void* const* d_in, const int* in_sizes, int n_in,
                              void* d_out, int out_size, void* d_ws, size_t ws_size,
                              hipStream_t stream) {
    const float* x    = (const float*)d_in[0];
    const float* Wemb = (const float*)d_in[1];
    const float* Wih1 = (const float*)d_in[2];
    const float* Whh1 = (const float*)d_in[3];
    const float* b1   = (const float*)d_in[4];
    const float* Wih2 = (const float*)d_in[5];
    // d_in[6] = Whh2: unused (h=c=0 at LSTM2's single step)
    const float* b2   = (const float*)d_in[7];
    const float* Wout = (const float*)d_in[8];
    const float* bout = (const float*)d_in[9];
    float* out = (float*)d_out;

    lstm_pipe_kernel<<<128, 512, 0, stream>>>(
        x, Wemb, Wih1, Whh1, b1, Wih2, b2, Wout, bout, out);
}

// Round 12
// 388.716 us; speedup vs baseline: 1.7411x; 1.7411x over previous
//
#include <hip/hip_runtime.h>

typedef _Float16 f16x8 __attribute__((ext_vector_type(8)));
typedef float    f32x4 __attribute__((ext_vector_type(4)));

#define NSTEP 512

// 7-trans LSTM activation (validated R8-R11: absmax 6.1e-5 over 512 steps).
__device__ __forceinline__ float lstm_act_(float gi, float gf, float gg, float go, float& c) {
    float eg = __expf(fminf(gg + gg, 21.0f));
    float ei = __expf(fminf(-gi, 21.0f));
    float ef = __expf(fminf(-gf, 21.0f));
    float eo = __expf(fminf(-go, 21.0f));
    float X  = (eg + 1.0f) * (1.0f + ei);
    float Y  = 1.0f + ef;
    float r  = __builtin_amdgcn_rcpf(X * Y);
    c = fmaf(r * X, c, (eg - 1.0f) * (r * Y));
    float ec = __expf(fminf(c + c, 21.0f));
    float r2 = __builtin_amdgcn_rcpf((ec + 1.0f) * (1.0f + eo));
    return (ec - 1.0f) * r2;
}
__device__ __forceinline__ float sig_(float v) {
    return __builtin_amdgcn_rcpf(1.0f + __expf(-v));
}
__device__ __forceinline__ float tanh_(float v) {
    return 1.0f - 2.0f * __builtin_amdgcn_rcpf(__expf(v + v) + 1.0f);
}

// 1024 threads = 16 waves (4/SIMD), grid 256 (1 block/CU), 16 batches/block.
// MINIMAL PER-WAVE WORK: wave tau owns exactly ONE 16x16 tile (units 4tau..4tau+3,
// tile-row = usub*4+gate). Lane (q,m): acc[r] = gate r of unit 4tau+q, batch m
// -> ONE activation per lane (7 trans). Per-wave per-step: 3 ds_read_b128 +
// 6 MFMA + 4 fma combine + 1 act + 1 b16 write. Half of R9's per-CU VALU content.
// Panel: K=96 fragment-major P[buf][kc][q][batch][jj]; k = kc*32+q*8+jj;
// k<20 = emb, 20<=k<84 = h unit k-20, k>=84 pad (weight rows are ZERO there, so
// pad content is multiplied by 0 -> no maintenance). Emb computed by 320 writer
// threads straight into the panel (amortized ~1 op/lane; no per-lane ef build).
// Precision: f16 2-pass weight split W = Whi + Wlo*2^-11 (R6/R9 lineage).
__global__ __launch_bounds__(1024, 1) void lstm_mfma16_kernel(
    const float* __restrict__ x,     const float* __restrict__ Wemb,
    const float* __restrict__ Wih1,  const float* __restrict__ Whh1,
    const float* __restrict__ b1,    const float* __restrict__ Wih2,
    const float* __restrict__ b2,    const float* __restrict__ Wout,
    const float* __restrict__ bout,  float* __restrict__ out)
{
    __shared__ __align__(16) _Float16 P[2][3][4][16][8];   // 6144 B
    __shared__ __align__(16) float h2tmp[16 * 64];         // 4096 B
    __shared__ __align__(16) float h2s[256 * 16];          // 16384 B
    __shared__ float part[64 * 16 * 2];                    // 8192 B

    const int t   = threadIdx.x;
    const int l   = t & 63;
    const int tau = t >> 6;      // wave = tile 0..15
    const int m   = l & 15;      // A-row / B col (batch) / D col
    const int q   = l >> 4;      // quad: D rows q*4+r ; B-frag k = kc*32+q*8+jj
    const int b0  = blockIdx.x * 16;

    // ---- weight fragments (f16 hi + lo*2048), one tile ---------------------
    f16x8 wh[3], wl[3];
    {
        const int n = (m & 3) * 64 + 4 * tau + (m >> 2);   // gate-matrix row
        #pragma unroll
        for (int c = 0; c < 3; ++c) {
            #pragma unroll
            for (int jj = 0; jj < 8; ++jj) {
                int k = c * 32 + (q << 3) + jj;
                float v = 0.0f;
                if (k < 20)      v = Wih1[n * 20 + k];
                else if (k < 84) v = Whh1[n * 64 + (k - 20)];
                _Float16 hi = (_Float16)v;
                wh[c][jj] = hi;
                wl[c][jj] = (_Float16)((v - (float)hi) * 2048.0f);
            }
        }
    }
    f32x4 bias4;
    #pragma unroll
    for (int r = 0; r < 4; ++r) bias4[r] = b1[r * 64 + 4 * tau + q];
    const f32x4 z4 = {0.f, 0.f, 0.f, 0.f};

    // lane's act cell: (unit myu, batch m); panel write coords for h
    const int myu = 4 * tau + q;
    const int wk  = 20 + myu;
    const int wkc = wk >> 5, wq = (wk >> 3) & 3, wjj = wk & 7;

    // ---- emb writers: t<320 -> (be=t&15, ee=t>>4 in 0..19) -----------------
    const int be = t & 15;
    const int ee = t >> 4;
    const bool embp = (t < 320);
    const float* xrow = x + (size_t)(b0 + be) * (2 * NSTEP);
    float we0 = 0.f, we1 = 0.f;
    if (embp) { we0 = Wemb[ee * 2]; we1 = Wemb[ee * 2 + 1]; }

    // ---- zero both buffers once (pads read-but-zero-weighted; h/emb cells
    //      overwritten every step) -------------------------------------------
    for (int idx = t; idx < 2 * 3 * 4 * 16 * 8; idx += 1024)
        ((_Float16*)P)[idx] = (_Float16)0.0f;
    __syncthreads();
    if (embp)
        P[0][0][ee >> 3][be][ee & 7] =
            (_Float16)fmaxf(xrow[0] * we0 + xrow[1] * we1, 0.0f);
    float xa = 0.f, xb = 0.f;
    if (embp) { xa = xrow[2]; xb = xrow[3]; }   // token 1
    __syncthreads();

    // ---- main recurrence ----------------------------------------------------
    float cst = 0.f;
    int cur = 0;

    for (int i = 0; i < NSTEP; ++i) {
        // B-frags: 3 planes, lane-linear (base + laneid*16B within plane)
        const _Float16* base = &P[cur][0][q][m][0];
        f16x8 f0 = *(const f16x8*)(base);
        f16x8 f1 = *(const f16x8*)(base + 512);
        f16x8 f2 = *(const f16x8*)(base + 1024);

        f32x4 a0, a1;
        a0 = __builtin_amdgcn_mfma_f32_16x16x32_f16(wh[0], f0, bias4, 0, 0, 0);
        a1 = __builtin_amdgcn_mfma_f32_16x16x32_f16(wl[0], f0, z4, 0, 0, 0);
        a0 = __builtin_amdgcn_mfma_f32_16x16x32_f16(wh[1], f1, a0, 0, 0, 0);
        a1 = __builtin_amdgcn_mfma_f32_16x16x32_f16(wl[1], f1, a1, 0, 0, 0);
        a0 = __builtin_amdgcn_mfma_f32_16x16x32_f16(wh[2], f2, a0, 0, 0, 0);
        a1 = __builtin_amdgcn_mfma_f32_16x16x32_f16(wl[2], f2, a1, 0, 0, 0);

        // one activation per lane
        float gi = fmaf(0x1p-11f, a1[0], a0[0]);
        float gf = fmaf(0x1p-11f, a1[1], a0[1]);
        float gg = fmaf(0x1p-11f, a1[2], a0[2]);
        float go = fmaf(0x1p-11f, a1[3], a0[3]);
        float hv = lstm_act_(gi, gf, gg, go, cst);

        const int nxt = cur ^ 1;
        P[nxt][wkc][wq][m][wjj] = (_Float16)hv;
        if (embp) {
            P[nxt][0][ee >> 3][be][ee & 7] =
                (_Float16)fmaxf(fmaf(xa, we0, xb * we1), 0.0f);
            int ns = (i + 2 < NSTEP) ? i + 2 : NSTEP - 1;
            xa = xrow[2 * ns]; xb = xrow[2 * ns + 1];
        }
        __syncthreads();
        cur = nxt;
    }
    // final h(511) in P[cur]

    // ---- epilogue: h64 to fp32 (1024 values, one per thread) ---------------
    {
        int b = t >> 6, k = t & 63, kk = 20 + k;
        h2tmp[t] = (float)P[cur][kk >> 5][(kk >> 3) & 3][b][kk & 7];
    }
    __syncthreads();

    // ---- LSTM2 (single step, h=c=0 -> f-gate irrelevant) -------------------
    {
        const int u = t & 255;
        const int bh0 = (t >> 8) * 4;            // 4 batches per thread-quarter
        float acci[4], accg[4], acco[4];
        float bi2 = b2[u], bg2 = b2[512 + u], bo2 = b2[768 + u];
        #pragma unroll
        for (int b = 0; b < 4; ++b) { acci[b] = bi2; accg[b] = bg2; acco[b] = bo2; }
        for (int k4 = 0; k4 < 64; k4 += 4) {
            float4 wi = *(const float4*)&Wih2[(size_t)u * 64 + k4];
            float4 wg = *(const float4*)&Wih2[(size_t)(512 + u) * 64 + k4];
            float4 wo = *(const float4*)&Wih2[(size_t)(768 + u) * 64 + k4];
            #pragma unroll
            for (int b = 0; b < 4; ++b) {
                float4 hb = *(const float4*)&h2tmp[(bh0 + b) * 64 + k4];
                acci[b] += wi.x * hb.x + wi.y * hb.y + wi.z * hb.z + wi.w * hb.w;
                accg[b] += wg.x * hb.x + wg.y * hb.y + wg.z * hb.z + wg.w * hb.w;
                acco[b] += wo.x * hb.x + wo.y * hb.y + wo.z * hb.z + wo.w * hb.w;
            }
        }
        #pragma unroll
        for (int b = 0; b < 4; ++b) {
            float c2 = sig_(acci[b]) * tanh_(accg[b]);
            h2s[u * 16 + bh0 + b] = sig_(acco[b]) * tanh_(c2);
        }
    }
    __syncthreads();

    // ---- output projection --------------------------------------------------
    {
        int b = t & 15, grp = t >> 4;            // 64 groups x 4 units
        float p0 = 0.f, p1 = 0.f;
        #pragma unroll
        for (int uu = grp * 4; uu < grp * 4 + 4; ++uu) {
            float hvv = h2s[uu * 16 + b];
            p0 += hvv * Wout[uu];
            p1 += hvv * Wout[256 + uu];
        }
        part[(grp * 16 + b) * 2 + 0] = p0;
        part[(grp * 16 + b) * 2 + 1] = p1;
    }
    __syncthreads();
    if (t < 32) {
        int b = t >> 1, o = t & 1;
        float s0 = bout[o];
        for (int grp = 0; grp < 64; ++grp) s0 += part[(grp * 16 + b) * 2 + o];
        out[(size_t)(b0 + b) * 2 + o] = s0;
    }
}

extern "C" void kernel_launch(void* const* d_in, const int* in_sizes, int n_in,
                              void* d_out, int out_size, void* d_ws, size_t ws_size,
                              hipStream_t stream) {
    const float* x    = (const float*)d_in[0];
    const float* Wemb = (const float*)d_in[1];
    const float* Wih1 = (const float*)d_in[2];
    const float* Whh1 = (const float*)d_in[3];
    const float* b1   = (const float*)d_in[4];
    const float* Wih2 = (const float*)d_in[5];
    // d_in[6] = Whh2: unused (h=c=0 at LSTM2's single step)
    const float* b2   = (const float*)d_in[7];
    const float* Wout = (const float*)d_in[8];
    const float* bout = (const float*)d_in[9];
    float* out = (float*)d_out;

    lstm_mfma16_kernel<<<256, 1024, 0, stream>>>(
        x, Wemb, Wih1, Whh1, b1, Wih2, b2, Wout, bout, out);
}

// Round 13
// 338.258 us; speedup vs baseline: 2.0008x; 1.1492x over previous
//
#include <hip/hip_runtime.h>

typedef _Float16 f16x8 __attribute__((ext_vector_type(8)));
typedef float    f32x4 __attribute__((ext_vector_type(4)));

#define NSTEP 512

// 7-trans LSTM activation (validated R8-R12: absmax 6.1e-5 over 512 steps).
__device__ __forceinline__ float lstm_act_(float gi, float gf, float gg, float go, float& c) {
    float eg = __expf(fminf(gg + gg, 21.0f));
    float ei = __expf(fminf(-gi, 21.0f));
    float ef = __expf(fminf(-gf, 21.0f));
    float eo = __expf(fminf(-go, 21.0f));
    float X  = (eg + 1.0f) * (1.0f + ei);
    float Y  = 1.0f + ef;
    float r  = __builtin_amdgcn_rcpf(X * Y);
    c = fmaf(r * X, c, (eg - 1.0f) * (r * Y));
    float ec = __expf(fminf(c + c, 21.0f));
    float r2 = __builtin_amdgcn_rcpf((ec + 1.0f) * (1.0f + eo));
    return (ec - 1.0f) * r2;
}
__device__ __forceinline__ float sig_(float v) {
    return __builtin_amdgcn_rcpf(1.0f + __expf(-v));
}
__device__ __forceinline__ float tanh_(float v) {
    return 1.0f - 2.0f * __builtin_amdgcn_rcpf(__expf(v + v) + 1.0f);
}

// 1024 threads = 16 waves (4/SIMD), grid 256 (1 block/CU), 16 batches/block.
// R12 skeleton: wave tau owns ONE 16x16 tile (units 4tau..4tau+3, tile-row =
// usub*4+gate); lane (q,m): acc[r] = gate r of unit 4tau+q, batch m -> ONE
// activation per lane. Panel K=96 fragment-major P[buf][kc][q][batch][jj]
// (lane-linear conflict-free ds_read_b128); emb written straight into panel
// by 320 writer threads.
// R13 change: SINGLE-PASS f16 weights (W -> f16 RTN, no lo-correction chain).
// Per-wave per-step: 3 ds_read + 3 MFMA (bias-seeded chain) + 1 act + 1 write.
// Halves matrix-pipe busy (was ~40% of per-SIMD cycles) and kills the combine
// fmas. Accuracy: W-quant noise ~= existing A-quant noise -> absmax ~1e-4
// predicted vs 2.94e-4 threshold (revert to 2-pass if exceeded).
__global__ __launch_bounds__(1024, 1) void lstm_mfma16_kernel(
    const float* __restrict__ x,     const float* __restrict__ Wemb,
    const float* __restrict__ Wih1,  const float* __restrict__ Whh1,
    const float* __restrict__ b1,    const float* __restrict__ Wih2,
    const float* __restrict__ b2,    const float* __restrict__ Wout,
    const float* __restrict__ bout,  float* __restrict__ out)
{
    __shared__ __align__(16) _Float16 P[2][3][4][16][8];   // 6144 B
    __shared__ __align__(16) float h2tmp[16 * 64];         // 4096 B
    __shared__ __align__(16) float h2s[256 * 16];          // 16384 B
    __shared__ float part[64 * 16 * 2];                    // 8192 B

    const int t   = threadIdx.x;
    const int l   = t & 63;
    const int tau = t >> 6;      // wave = tile 0..15
    const int m   = l & 15;      // A-row / B col (batch) / D col
    const int q   = l >> 4;      // quad: D rows q*4+r ; B-frag k = kc*32+q*8+jj
    const int b0  = blockIdx.x * 16;

    // ---- weight fragments (single f16 copy), one tile ----------------------
    f16x8 wh[3];
    {
        const int n = (m & 3) * 64 + 4 * tau + (m >> 2);   // gate-matrix row
        #pragma unroll
        for (int c = 0; c < 3; ++c) {
            #pragma unroll
            for (int jj = 0; jj < 8; ++jj) {
                int k = c * 32 + (q << 3) + jj;
                float v = 0.0f;
                if (k < 20)      v = Wih1[n * 20 + k];
                else if (k < 84) v = Whh1[n * 64 + (k - 20)];
                wh[c][jj] = (_Float16)v;
            }
        }
    }
    f32x4 bias4;
    #pragma unroll
    for (int r = 0; r < 4; ++r) bias4[r] = b1[r * 64 + 4 * tau + q];

    // lane's act cell: (unit myu, batch m); panel write coords for h
    const int myu = 4 * tau + q;
    const int wk  = 20 + myu;
    const int wkc = wk >> 5, wq = (wk >> 3) & 3, wjj = wk & 7;

    // ---- emb writers: t<320 -> (be=t&15, ee=t>>4 in 0..19) -----------------
    const int be = t & 15;
    const int ee = t >> 4;
    const bool embp = (t < 320);
    const float* xrow = x + (size_t)(b0 + be) * (2 * NSTEP);
    float we0 = 0.f, we1 = 0.f;
    if (embp) { we0 = Wemb[ee * 2]; we1 = Wemb[ee * 2 + 1]; }

    // ---- zero both buffers once --------------------------------------------
    for (int idx = t; idx < 2 * 3 * 4 * 16 * 8; idx += 1024)
        ((_Float16*)P)[idx] = (_Float16)0.0f;
    __syncthreads();
    if (embp)
        P[0][0][ee >> 3][be][ee & 7] =
            (_Float16)fmaxf(xrow[0] * we0 + xrow[1] * we1, 0.0f);
    float xa = 0.f, xb = 0.f;
    if (embp) { xa = xrow[2]; xb = xrow[3]; }   // token 1
    __syncthreads();

    // ---- main recurrence ----------------------------------------------------
    float cst = 0.f;
    int cur = 0;

    for (int i = 0; i < NSTEP; ++i) {
        // B-frags: 3 planes, lane-linear (base + laneid*16B within plane)
        const _Float16* base = &P[cur][0][q][m][0];
        f16x8 f0 = *(const f16x8*)(base);
        f16x8 f1 = *(const f16x8*)(base + 512);
        f16x8 f2 = *(const f16x8*)(base + 1024);

        f32x4 a0;
        a0 = __builtin_amdgcn_mfma_f32_16x16x32_f16(wh[0], f0, bias4, 0, 0, 0);
        a0 = __builtin_amdgcn_mfma_f32_16x16x32_f16(wh[1], f1, a0, 0, 0, 0);
        a0 = __builtin_amdgcn_mfma_f32_16x16x32_f16(wh[2], f2, a0, 0, 0, 0);

        // one activation per lane (gates = a0 directly)
        float hv = lstm_act_(a0[0], a0[1], a0[2], a0[3], cst);

        const int nxt = cur ^ 1;
        P[nxt][wkc][wq][m][wjj] = (_Float16)hv;
        if (embp) {
            P[nxt][0][ee >> 3][be][ee & 7] =
                (_Float16)fmaxf(fmaf(xa, we0, xb * we1), 0.0f);
            int ns = (i + 2 < NSTEP) ? i + 2 : NSTEP - 1;
            xa = xrow[2 * ns]; xb = xrow[2 * ns + 1];
        }
        __syncthreads();
        cur = nxt;
    }
    // final h(511) in P[cur]

    // ---- epilogue: h64 to fp32 (1024 values, one per thread) ---------------
    {
        int b = t >> 6, k = t & 63, kk = 20 + k;
        h2tmp[t] = (float)P[cur][kk >> 5][(kk >> 3) & 3][b][kk & 7];
    }
    __syncthreads();

    // ---- LSTM2 (single step, h=c=0 -> f-gate irrelevant) -------------------
    {
        const int u = t & 255;
        const int bh0 = (t >> 8) * 4;            // 4 batches per thread-quarter
        float acci[4], accg[4], acco[4];
        float bi2 = b2[u], bg2 = b2[512 + u], bo2 = b2[768 + u];
        #pragma unroll
        for (int b = 0; b < 4; ++b) { acci[b] = bi2; accg[b] = bg2; acco[b] = bo2; }
        for (int k4 = 0; k4 < 64; k4 += 4) {
            float4 wi = *(const float4*)&Wih2[(size_t)u * 64 + k4];
            float4 wg = *(const float4*)&Wih2[(size_t)(512 + u) * 64 + k4];
            float4 wo = *(const float4*)&Wih2[(size_t)(768 + u) * 64 + k4];
            #pragma unroll
            for (int b = 0; b < 4; ++b) {
                float4 hb = *(const float4*)&h2tmp[(bh0 + b) * 64 + k4];
                acci[b] += wi.x * hb.x + wi.y * hb.y + wi.z * hb.z + wi.w * hb.w;
                accg[b] += wg.x * hb.x + wg.y * hb.y + wg.z * hb.z + wg.w * hb.w;
                acco[b] += wo.x * hb.x + wo.y * hb.y + wo.z * hb.z + wo.w * hb.w;
            }
        }
        #pragma unroll
        for (int b = 0; b < 4; ++b) {
            float c2 = sig_(acci[b]) * tanh_(accg[b]);
            h2s[u * 16 + bh0 + b] = sig_(acco[b]) * tanh_(c2);
        }
    }
    __syncthreads();

    // ---- output projection --------------------------------------------------
    {
        int b = t & 15, grp = t >> 4;            // 64 groups x 4 units
        float p0 = 0.f, p1 = 0.f;
        #pragma unroll
        for (int uu = grp * 4; uu < grp * 4 + 4; ++uu) {
            float hvv = h2s[uu * 16 + b];
            p0 += hvv * Wout[uu];
            p1 += hvv * Wout[256 + uu];
        }
        part[(grp * 16 + b) * 2 + 0] = p0;
        part[(grp * 16 + b) * 2 + 1] = p1;
    }
    __syncthreads();
    if (t < 32) {
        int b = t >> 1, o = t & 1;
        float s0 = bout[o];
        for (int grp = 0; grp < 64; ++grp) s0 += part[(grp * 16 + b) * 2 + o];
        out[(size_t)(b0 + b) * 2 + o] = s0;
    }
}

extern "C" void kernel_launch(void* const* d_in, const int* in_sizes, int n_in,
                              void* d_out, int out_size, void* d_ws, size_t ws_size,
                              hipStream_t stream) {
    const float* x    = (const float*)d_in[0];
    const float* Wemb = (const float*)d_in[1];
    const float* Wih1 = (const float*)d_in[2];
    const float* Whh1 = (const float*)d_in[3];
    const float* b1   = (const float*)d_in[4];
    const float* Wih2 = (const float*)d_in[5];
    // d_in[6] = Whh2: unused (h=c=0 at LSTM2's single step)
    const float* b2   = (const float*)d_in[7];
    const float* Wout = (const float*)d_in[8];
    const float* bout = (const float*)d_in[9];
    float* out = (float*)d_out;

    lstm_mfma16_kernel<<<256, 1024, 0, stream>>>(
        x, Wemb, Wih1, Whh1, b1, Wih2, b2, Wout, bout, out);
}

// Round 14
// 334.142 us; speedup vs baseline: 2.0254x; 1.0123x over previous
//
#include <hip/hip_runtime.h>

typedef _Float16 f16x8 __attribute__((ext_vector_type(8)));
typedef float    f32x4 __attribute__((ext_vector_type(4)));

#define NSTEP 512

// Clamp-free 7-trans LSTM activation. Bounds (proven from |W|<=1/8, |a|<=1,
// 84 terms + bias): |preact| <= 10.7 -> e^{2g} <= 1.8e9, X*Y <= 3e18, no fp32
// overflow; expf underflow->0 gives exact saturation. Only c is unbounded ->
// keep the single fmin on ec. exp(-x) negation folds into the exp src modifier.
__device__ __forceinline__ float lstm_act_(float gi, float gf, float gg, float go, float& c) {
    float eg = __expf(gg + gg);
    float ei = __expf(-gi);
    float ef = __expf(-gf);
    float eo = __expf(-go);
    float X  = (eg + 1.0f) * (1.0f + ei);
    float Y  = 1.0f + ef;
    float r  = __builtin_amdgcn_rcpf(X * Y);
    c = fmaf(r * X, c, (eg - 1.0f) * (r * Y));
    float ec = __expf(fminf(c + c, 21.0f));
    float r2 = __builtin_amdgcn_rcpf((ec + 1.0f) * (1.0f + eo));
    return (ec - 1.0f) * r2;
}
__device__ __forceinline__ float sig_(float v) {
    return __builtin_amdgcn_rcpf(1.0f + __expf(-v));
}
__device__ __forceinline__ float tanh_(float v) {
    return 1.0f - 2.0f * __builtin_amdgcn_rcpf(__expf(v + v) + 1.0f);
}

// 1024 threads = 16 waves (4/SIMD), grid 256 (1 block/CU), 16 batches/block.
// R13 skeleton: wave tau owns ONE 16x16 tile (units 4tau..4tau+3, tile-row =
// usub*4+gate); lane (q,m): acc[r] = gate r of unit 4tau+q, batch m -> ONE
// activation/lane. Panel K=96 fragment-major P[buf][kc][q][batch][jj],
// lane-linear conflict-free ds_read_b128. Single-pass f16 weights (R13-proven:
// absmax pinned at 2^-14 by f16 h-storage, weight quant invisible).
// R14: (1) clamp-free act; (2) BALANCED emb writers - lanes 0..19 of wave tau
// write batch tau's 20 emb cells (every wave same light load -> tight barrier
// arrival; 1 broadcast x-line per wave); (3) 2 independent MFMA chains
// (depth 2) + 4 adds.
__global__ __launch_bounds__(1024, 1) void lstm_mfma16_kernel(
    const float* __restrict__ x,     const float* __restrict__ Wemb,
    const float* __restrict__ Wih1,  const float* __restrict__ Whh1,
    const float* __restrict__ b1,    const float* __restrict__ Wih2,
    const float* __restrict__ b2,    const float* __restrict__ Wout,
    const float* __restrict__ bout,  float* __restrict__ out)
{
    __shared__ __align__(16) _Float16 P[2][3][4][16][8];   // 6144 B
    __shared__ __align__(16) float h2tmp[16 * 64];         // 4096 B
    __shared__ __align__(16) float h2s[256 * 16];          // 16384 B
    __shared__ float part[64 * 16 * 2];                    // 8192 B

    const int t   = threadIdx.x;
    const int l   = t & 63;
    const int tau = t >> 6;      // wave = tile 0..15 (also: emb batch row tau)
    const int m   = l & 15;      // A-row / B col (batch) / D col
    const int q   = l >> 4;      // quad: D rows q*4+r ; B-frag k = kc*32+q*8+jj
    const int b0  = blockIdx.x * 16;

    // ---- weight fragments (single f16 copy), one tile ----------------------
    f16x8 wh[3];
    {
        const int n = (m & 3) * 64 + 4 * tau + (m >> 2);   // gate-matrix row
        #pragma unroll
        for (int c = 0; c < 3; ++c) {
            #pragma unroll
            for (int jj = 0; jj < 8; ++jj) {
                int k = c * 32 + (q << 3) + jj;
                float v = 0.0f;
                if (k < 20)      v = Wih1[n * 20 + k];
                else if (k < 84) v = Whh1[n * 64 + (k - 20)];
                wh[c][jj] = (_Float16)v;
            }
        }
    }
    f32x4 bias4;
    #pragma unroll
    for (int r = 0; r < 4; ++r) bias4[r] = b1[r * 64 + 4 * tau + q];
    const f32x4 z4 = {0.f, 0.f, 0.f, 0.f};

    // lane's act cell: (unit myu, batch m); panel write coords for h
    const int myu = 4 * tau + q;
    const int wk  = 20 + myu;
    const int wkc = wk >> 5, wq = (wk >> 3) & 3, wjj = wk & 7;

    // ---- balanced emb writers: lanes 0..19 of wave tau -> batch tau --------
    const bool embp = (l < 20);
    const int ee = l;                                  // emb dim (valid when embp)
    const float* xrow = x + (size_t)(b0 + tau) * (2 * NSTEP);
    float we0 = 0.f, we1 = 0.f;
    if (embp) { we0 = Wemb[2 * l]; we1 = Wemb[2 * l + 1]; }

    // ---- zero both buffers once --------------------------------------------
    for (int idx = t; idx < 2 * 3 * 4 * 16 * 8; idx += 1024)
        ((_Float16*)P)[idx] = (_Float16)0.0f;
    __syncthreads();
    if (embp)
        P[0][0][ee >> 3][tau][ee & 7] =
            (_Float16)fmaxf(xrow[0] * we0 + xrow[1] * we1, 0.0f);
    float xa = 0.f, xb = 0.f;
    if (embp) { xa = xrow[2]; xb = xrow[3]; }   // token 1
    __syncthreads();

    // ---- main recurrence ----------------------------------------------------
    float cst = 0.f;
    int cur = 0;

    for (int i = 0; i < NSTEP; ++i) {
        // B-frags: 3 planes, lane-linear (base + laneid*16B within plane)
        const _Float16* base = &P[cur][0][q][m][0];
        f16x8 f0 = *(const f16x8*)(base);
        f16x8 f1 = *(const f16x8*)(base + 512);
        f16x8 f2 = *(const f16x8*)(base + 1024);

        // two independent chains (depth 2), combined with 4 adds
        f32x4 a0 = __builtin_amdgcn_mfma_f32_16x16x32_f16(wh[0], f0, bias4, 0, 0, 0);
        f32x4 a1 = __builtin_amdgcn_mfma_f32_16x16x32_f16(wh[1], f1, z4, 0, 0, 0);
        a0 = __builtin_amdgcn_mfma_f32_16x16x32_f16(wh[2], f2, a0, 0, 0, 0);

        float hv = lstm_act_(a0[0] + a1[0], a0[1] + a1[1],
                             a0[2] + a1[2], a0[3] + a1[3], cst);

        const int nxt = cur ^ 1;
        P[nxt][wkc][wq][m][wjj] = (_Float16)hv;
        if (embp) {
            P[nxt][0][ee >> 3][tau][ee & 7] =
                (_Float16)fmaxf(fmaf(xa, we0, xb * we1), 0.0f);
            int ns = (i + 2 < NSTEP) ? i + 2 : NSTEP - 1;
            xa = xrow[2 * ns]; xb = xrow[2 * ns + 1];
        }
        __syncthreads();
        cur = nxt;
    }
    // final h(511) in P[cur]

    // ---- epilogue: h64 to fp32 (1024 values, one per thread) ---------------
    {
        int b = t >> 6, k = t & 63, kk = 20 + k;
        h2tmp[t] = (float)P[cur][kk >> 5][(kk >> 3) & 3][b][kk & 7];
    }
    __syncthreads();

    // ---- LSTM2 (single step, h=c=0 -> f-gate irrelevant) -------------------
    {
        const int u = t & 255;
        const int bh0 = (t >> 8) * 4;            // 4 batches per thread-quarter
        float acci[4], accg[4], acco[4];
        float bi2 = b2[u], bg2 = b2[512 + u], bo2 = b2[768 + u];
        #pragma unroll
        for (int b = 0; b < 4; ++b) { acci[b] = bi2; accg[b] = bg2; acco[b] = bo2; }
        for (int k4 = 0; k4 < 64; k4 += 4) {
            float4 wi = *(const float4*)&Wih2[(size_t)u * 64 + k4];
            float4 wg = *(const float4*)&Wih2[(size_t)(512 + u) * 64 + k4];
            float4 wo = *(const float4*)&Wih2[(size_t)(768 + u) * 64 + k4];
            #pragma unroll
            for (int b = 0; b < 4; ++b) {
                float4 hb = *(const float4*)&h2tmp[(bh0 + b) * 64 + k4];
                acci[b] += wi.x * hb.x + wi.y * hb.y + wi.z * hb.z + wi.w * hb.w;
                accg[b] += wg.x * hb.x + wg.y * hb.y + wg.z * hb.z + wg.w * hb.w;
                acco[b] += wo.x * hb.x + wo.y * hb.y + wo.z * hb.z + wo.w * hb.w;
            }
        }
        #pragma unroll
        for (int b = 0; b < 4; ++b) {
            float c2 = sig_(acci[b]) * tanh_(accg[b]);
            h2s[u * 16 + bh0 + b] = sig_(acco[b]) * tanh_(c2);
        }
    }
    __syncthreads();

    // ---- output projection --------------------------------------------------
    {
        int b = t & 15, grp = t >> 4;            // 64 groups x 4 units
        float p0 = 0.f, p1 = 0.f;
        #pragma unroll
        for (int uu = grp * 4; uu < grp * 4 + 4; ++uu) {
            float hvv = h2s[uu * 16 + b];
            p0 += hvv * Wout[uu];
            p1 += hvv * Wout[256 + uu];
        }
        part[(grp * 16 + b) * 2 + 0] = p0;
        part[(grp * 16 + b) * 2 + 1] = p1;
    }
    __syncthreads();
    if (t < 32) {
        int b = t >> 1, o = t & 1;
        float s0 = bout[o];
        for (int grp = 0; grp < 64; ++grp) s0 += part[(grp * 16 + b) * 2 + o];
        out[(size_t)(b0 + b) * 2 + o] = s0;
    }
}

extern "C" void kernel_launch(void* const* d_in, const int* in_sizes, int n_in,
                              void* d_out, int out_size, void* d_ws, size_t ws_size,
                              hipStream_t stream) {
    const float* x    = (const float*)d_in[0];
    const float* Wemb = (const float*)d_in[1];
    const float* Wih1 = (const float*)d_in[2];
    const float* Whh1 = (const float*)d_in[3];
    const float* b1   = (const float*)d_in[4];
    const float* Wih2 = (const float*)d_in[5];
    // d_in[6] = Whh2: unused (h=c=0 at LSTM2's single step)
    const float* b2   = (const float*)d_in[7];
    const float* Wout = (const float*)d_in[8];
    const float* bout = (const float*)d_in[9];
    float* out = (float*)d_out;

    lstm_mfma16_kernel<<<256, 1024, 0, stream>>>(
        x, Wemb, Wih1, Whh1, b1, Wih2, b2, Wout, bout, out);
}

// Round 15
// 317.661 us; speedup vs baseline: 2.1305x; 1.0519x over previous
//
#include <hip/hip_runtime.h>

typedef _Float16 f16x8 __attribute__((ext_vector_type(8)));
typedef float    f32x4 __attribute__((ext_vector_type(4)));

#define NSTEP 512
#define LOG2E     1.4426950408889634f
#define TWOLOG2E  2.8853900817779268f

__device__ __forceinline__ float exp2_(float v) { return __builtin_amdgcn_exp2f(v); }

// Exp2-domain 7-trans LSTM activation. Gates arrive PRE-SCALED from the MFMA:
// gi,gf,go = -log2(e)*(preact), gg = +2log2(e)*(preact). So every gate exp is a
// raw v_exp_f32 (2^x) with zero preprocessing. c stays in linear domain; its
// exp needs one mul (c*2log2e) + the single guard fmin (c is the only unbounded
// quantity; gate args bounded: |preact|<=10.7 -> |gg|<=31, exp2-safe).
__device__ __forceinline__ float lstm_act_(float gi, float gf, float gg, float go, float& c) {
    float eg = exp2_(gg);
    float ei = exp2_(gi);
    float ef = exp2_(gf);
    float eo = exp2_(go);
    float X  = (eg + 1.0f) * (1.0f + ei);
    float Y  = 1.0f + ef;
    float r  = __builtin_amdgcn_rcpf(X * Y);
    c = fmaf(r * X, c, (eg - 1.0f) * (r * Y));
    float ec = exp2_(fminf(c * TWOLOG2E, 30.0f));
    float r2 = __builtin_amdgcn_rcpf((ec + 1.0f) * (1.0f + eo));
    return (ec - 1.0f) * r2;
}
__device__ __forceinline__ float sig_(float v) {
    return __builtin_amdgcn_rcpf(1.0f + exp2_(-v * LOG2E));
}
__device__ __forceinline__ float tanh_(float v) {
    return 1.0f - 2.0f * __builtin_amdgcn_rcpf(exp2_(v * TWOLOG2E) + 1.0f);
}

// 1024 threads = 16 waves (4/SIMD), grid 256 (1 block/CU), 16 batches/block.
// Wave tau owns ONE 16x16 tile (units 4tau..4tau+3, tile-row = usub*4+gate);
// lane (q,m): acc[r] = gate r of unit 4tau+q, batch m -> ONE activation/lane.
// Panel K=96 fragment-major P[buf][kc][q][batch][jj] (lane-linear conflict-free
// ds_read_b128). Single-pass f16 weights (absmax pinned at 2^-14 by f16
// h-storage). Balanced emb writers: lanes 0..19 of wave tau -> batch tau.
// R15: exp2-domain weight folding — W,b rows for gates i,f,o scaled by -log2e,
// gate g rows by +2log2e; all 4 gate exps become raw v_exp_f32.
__global__ __launch_bounds__(1024, 1) void lstm_mfma16_kernel(
    const float* __restrict__ x,     const float* __restrict__ Wemb,
    const float* __restrict__ Wih1,  const float* __restrict__ Whh1,
    const float* __restrict__ b1,    const float* __restrict__ Wih2,
    const float* __restrict__ b2,    const float* __restrict__ Wout,
    const float* __restrict__ bout,  float* __restrict__ out)
{
    __shared__ __align__(16) _Float16 P[2][3][4][16][8];   // 6144 B
    __shared__ __align__(16) float h2tmp[16 * 64];         // 4096 B
    __shared__ __align__(16) float h2s[256 * 16];          // 16384 B
    __shared__ float part[64 * 16 * 2];                    // 8192 B

    const int t   = threadIdx.x;
    const int l   = t & 63;
    const int tau = t >> 6;      // wave = tile 0..15 (also emb batch row)
    const int m   = l & 15;      // A-row / B col (batch) / D col
    const int q   = l >> 4;      // quad
    const int b0  = blockIdx.x * 16;

    // ---- weight fragments (single f16 copy, exp2-domain scaled) ------------
    f16x8 wh[3];
    {
        const int g = m & 3;                               // gate of this A-row
        const float sc = (g == 2) ? TWOLOG2E : -LOG2E;     // i,f,o:-log2e  g:+2log2e
        const int n = g * 64 + 4 * tau + (m >> 2);         // gate-matrix row
        #pragma unroll
        for (int c = 0; c < 3; ++c) {
            #pragma unroll
            for (int jj = 0; jj < 8; ++jj) {
                int k = c * 32 + (q << 3) + jj;
                float v = 0.0f;
                if (k < 20)      v = Wih1[n * 20 + k];
                else if (k < 84) v = Whh1[n * 64 + (k - 20)];
                wh[c][jj] = (_Float16)(v * sc);
            }
        }
    }
    f32x4 bias4;
    #pragma unroll
    for (int r = 0; r < 4; ++r) {
        float sc = (r == 2) ? TWOLOG2E : -LOG2E;
        bias4[r] = b1[r * 64 + 4 * tau + q] * sc;
    }
    const f32x4 z4 = {0.f, 0.f, 0.f, 0.f};

    // lane's act cell: (unit myu, batch m); panel write coords for h
    const int myu = 4 * tau + q;
    const int wk  = 20 + myu;
    const int wkc = wk >> 5, wq = (wk >> 3) & 3, wjj = wk & 7;

    // ---- balanced emb writers: lanes 0..19 of wave tau -> batch tau --------
    const bool embp = (l < 20);
    const int ee = l;
    const float* xrow = x + (size_t)(b0 + tau) * (2 * NSTEP);
    float we0 = 0.f, we1 = 0.f;
    if (embp) { we0 = Wemb[2 * l]; we1 = Wemb[2 * l + 1]; }

    // ---- zero both buffers once --------------------------------------------
    for (int idx = t; idx < 2 * 3 * 4 * 16 * 8; idx += 1024)
        ((_Float16*)P)[idx] = (_Float16)0.0f;
    __syncthreads();
    if (embp)
        P[0][0][ee >> 3][tau][ee & 7] =
            (_Float16)fmaxf(xrow[0] * we0 + xrow[1] * we1, 0.0f);
    float xa = 0.f, xb = 0.f;
    if (embp) { xa = xrow[2]; xb = xrow[3]; }   // token 1
    __syncthreads();

    // ---- main recurrence ----------------------------------------------------
    float cst = 0.f;
    int cur = 0;

    for (int i = 0; i < NSTEP; ++i) {
        const _Float16* base = &P[cur][0][q][m][0];
        f16x8 f0 = *(const f16x8*)(base);
        f16x8 f1 = *(const f16x8*)(base + 512);
        f16x8 f2 = *(const f16x8*)(base + 1024);

        // two independent chains (depth 2), combined with 4 adds
        f32x4 a0 = __builtin_amdgcn_mfma_f32_16x16x32_f16(wh[0], f0, bias4, 0, 0, 0);
        f32x4 a1 = __builtin_amdgcn_mfma_f32_16x16x32_f16(wh[1], f1, z4, 0, 0, 0);
        a0 = __builtin_amdgcn_mfma_f32_16x16x32_f16(wh[2], f2, a0, 0, 0, 0);

        float hv = lstm_act_(a0[0] + a1[0], a0[1] + a1[1],
                             a0[2] + a1[2], a0[3] + a1[3], cst);

        const int nxt = cur ^ 1;
        P[nxt][wkc][wq][m][wjj] = (_Float16)hv;
        if (embp) {
            P[nxt][0][ee >> 3][tau][ee & 7] =
                (_Float16)fmaxf(fmaf(xa, we0, xb * we1), 0.0f);
            int ns = (i + 2 < NSTEP) ? i + 2 : NSTEP - 1;
            xa = xrow[2 * ns]; xb = xrow[2 * ns + 1];
        }
        __syncthreads();
        cur = nxt;
    }
    // final h(511) in P[cur]

    // ---- epilogue: h64 to fp32 (1024 values, one per thread) ---------------
    {
        int b = t >> 6, k = t & 63, kk = 20 + k;
        h2tmp[t] = (float)P[cur][kk >> 5][(kk >> 3) & 3][b][kk & 7];
    }
    __syncthreads();

    // ---- LSTM2 (single step, h=c=0 -> f-gate irrelevant) -------------------
    {
        const int u = t & 255;
        const int bh0 = (t >> 8) * 4;
        float acci[4], accg[4], acco[4];
        float bi2 = b2[u], bg2 = b2[512 + u], bo2 = b2[768 + u];
        #pragma unroll
        for (int b = 0; b < 4; ++b) { acci[b] = bi2; accg[b] = bg2; acco[b] = bo2; }
        for (int k4 = 0; k4 < 64; k4 += 4) {
            float4 wi = *(const float4*)&Wih2[(size_t)u * 64 + k4];
            float4 wg = *(const float4*)&Wih2[(size_t)(512 + u) * 64 + k4];
            float4 wo = *(const float4*)&Wih2[(size_t)(768 + u) * 64 + k4];
            #pragma unroll
            for (int b = 0; b < 4; ++b) {
                float4 hb = *(const float4*)&h2tmp[(bh0 + b) * 64 + k4];
                acci[b] += wi.x * hb.x + wi.y * hb.y + wi.z * hb.z + wi.w * hb.w;
                accg[b] += wg.x * hb.x + wg.y * hb.y + wg.z * hb.z + wg.w * hb.w;
                acco[b] += wo.x * hb.x + wo.y * hb.y + wo.z * hb.z + wo.w * hb.w;
            }
        }
        #pragma unroll
        for (int b = 0; b < 4; ++b) {
            float c2 = sig_(acci[b]) * tanh_(accg[b]);
            h2s[u * 16 + bh0 + b] = sig_(acco[b]) * tanh_(c2);
        }
    }
    __syncthreads();

    // ---- output projection --------------------------------------------------
    {
        int b = t & 15, grp = t >> 4;            // 64 groups x 4 units
        float p0 = 0.f, p1 = 0.f;
        #pragma unroll
        for (int uu = grp * 4; uu < grp * 4 + 4; ++uu) {
            float hvv = h2s[uu * 16 + b];
            p0 += hvv * Wout[uu];
            p1 += hvv * Wout[256 + uu];
        }
        part[(grp * 16 + b) * 2 + 0] = p0;
        part[(grp * 16 + b) * 2 + 1] = p1;
    }
    __syncthreads();
    if (t < 32) {
        int b = t >> 1, o = t & 1;
        float s0 = bout[o];
        for (int grp = 0; grp < 64; ++grp) s0 += part[(grp * 16 + b) * 2 + o];
        out[(size_t)(b0 + b) * 2 + o] = s0;
    }
}

extern "C" void kernel_launch(void* const* d_in, const int* in_sizes, int n_in,
                              void* d_out, int out_size, void* d_ws, size_t ws_size,
                              hipStream_t stream) {
    const float* x    = (const float*)d_in[0];
    const float* Wemb = (const float*)d_in[1];
    const float* Wih1 = (const float*)d_in[2];
    const float* Whh1 = (const float*)d_in[3];
    const float* b1   = (const float*)d_in[4];
    const float* Wih2 = (const float*)d_in[5];
    // d_in[6] = Whh2: unused (h=c=0 at LSTM2's single step)
    const float* b2   = (const float*)d_in[7];
    const float* Wout = (const float*)d_in[8];
    const float* bout = (const float*)d_in[9];
    float* out = (float*)d_out;

    lstm_mfma16_kernel<<<256, 1024, 0, stream>>>(
        x, Wemb, Wih1, Whh1, b1, Wih2, b2, Wout, bout, out);
}